// Round 1
// baseline (4278.022 us; speedup 1.0000x reference)
//
#include <hip/hip_runtime.h>

namespace {

constexpr int kT = 2048;
constexpr int kH = 128;

__device__ __forceinline__ float fsigmoid(float x) {
    return 1.0f / (1.0f + __expf(-x));
}

__device__ __forceinline__ float ftanh(float x) {
    float xc = fminf(fmaxf(x, -15.0f), 15.0f);
    float e = __expf(2.0f * xc);
    return (e - 1.0f) / (e + 1.0f);
}

#define FMA4(acc, wrow, base)                      \
    acc = fmaf(v.x, wrow[(base) + 0], acc);        \
    acc = fmaf(v.y, wrow[(base) + 1], acc);        \
    acc = fmaf(v.z, wrow[(base) + 2], acc);        \
    acc = fmaf(v.w, wrow[(base) + 3], acc);

#define ST4(arr, base, vv)        \
    arr[(base) + 0] = (vv).x;     \
    arr[(base) + 1] = (vv).y;     \
    arr[(base) + 2] = (vv).z;     \
    arr[(base) + 3] = (vv).w;

#define ST4ADD(arr, base, va, vb)          \
    arr[(base) + 0] = (va).x + (vb).x;     \
    arr[(base) + 1] = (va).y + (vb).y;     \
    arr[(base) + 2] = (va).z + (vb).z;     \
    arr[(base) + 3] = (va).w + (vb).w;

// ---------------- encoder (one block per batch element) ----------------
// 512 threads. quartet j = tid>>2 in [0,128); s4 = tid&3;
// xh = s4>>1  (0: Wih rows / x input, 1: Whh rows / h input);
// sub = s4&1  (k-half). Thread holds rows {j, 128+j, 256+j} of its matrix,
// k in [64*sub, 64*sub+64)  -> 192 weight VGPRs, statically indexed.
__global__ __launch_bounds__(512, 2) void enc_kernel(
    const float* __restrict__ to_x, const int* __restrict__ lengths,
    const float* __restrict__ Wih, const float* __restrict__ Whh,
    const float* __restrict__ bih, const float* __restrict__ bhh,
    float* __restrict__ henc_out)
{
    __shared__ __align__(16) float smem[264];  // x at [0,128), h at [132,260): 4-bank offset
    constexpr int XO = 0, HO = 132;

    const int b   = blockIdx.x;
    const int tid = threadIdx.x;
    const int j   = tid >> 2;
    const int s4  = tid & 3;
    const int xh  = s4 >> 1;
    const int sub = s4 & 1;
    const int len = lengths[b];

    const float* W  = xh ? Whh : Wih;
    const float* bp = xh ? bhh : bih;

    float w[3][64];
#pragma unroll
    for (int r = 0; r < 3; ++r) {
        const float* rowp = W + (size_t)(r * kH + j) * kH + sub * 64;
#pragma unroll
        for (int k = 0; k < 64; k += 4) {
            const float4 v = *reinterpret_cast<const float4*>(rowp + k);
            ST4(w[r], k, v);
        }
    }
    const float bias0 = bp[j];
    const float bias1 = bp[kH + j];
    const float bias2 = bp[2 * kH + j];

    if (tid < kH) smem[HO + tid] = 0.0f;
    if (tid >= 128 && tid < 160) {
        const float4 v = *reinterpret_cast<const float4*>(
            to_x + (size_t)b * kT * kH + (tid - 128) * 4);
        *reinterpret_cast<float4*>(smem + XO + (tid - 128) * 4) = v;
    }
    __syncthreads();

    const float* src = smem + (xh ? HO : XO) + sub * 64;

    for (int t = 0; t < len; ++t) {
        float4 xf;
        const bool loader = (tid >= 480) && (t + 1 < len);
        if (loader) {
            xf = *reinterpret_cast<const float4*>(
                to_x + ((size_t)b * kT + t + 1) * kH + (tid - 480) * 4);
        }
        float a0 = 0.f, a1 = 0.f, a2 = 0.f;
#pragma unroll
        for (int c = 0; c < 16; ++c) {
            const float4 v = *reinterpret_cast<const float4*>(src + c * 4);
            FMA4(a0, w[0], c * 4);
            FMA4(a1, w[1], c * 4);
            FMA4(a2, w[2], c * 4);
        }
        // combine k-halves within the (xh) pair
        a0 += __shfl_xor(a0, 1);
        a1 += __shfl_xor(a1, 1);
        a2 += __shfl_xor(a2, 1);
        a0 += bias0; a1 += bias1; a2 += bias2;
        // exchange with the other xh pair (input-path <-> hidden-path)
        const float b0 = __shfl_xor(a0, 2);
        const float b1 = __shfl_xor(a1, 2);
        const float b2 = __shfl_xor(a2, 2);
        const float hq  = smem[HO + j];
        const float r   = fsigmoid(a0 + b0);
        const float z   = fsigmoid(a1 + b1);
        const float inn = xh ? b2 : a2;
        const float hn  = xh ? a2 : b2;
        const float n   = ftanh(inn + r * hn);
        const float hnew = (1.0f - z) * n + z * hq;
        __syncthreads();              // all LDS reads of this step done
        if (s4 == 0) smem[HO + j] = hnew;
        if (loader) *reinterpret_cast<float4*>(smem + XO + (tid - 480) * 4) = xf;
        __syncthreads();              // h / x ready for next step
    }

    // stash h_enc into out[b][0][:]
    if (tid < kH) henc_out[(size_t)b * kT * kH + tid] = smem[HO + tid];
}

// ---------------- fc + first decoder cell (one-shot) ----------------
// 64 blocks x 256 threads. Reads h_enc from out[b][0], writes y0 to out[b][1].
__global__ void y0_kernel(
    const float* __restrict__ fcW, const float* __restrict__ fcb,
    const float* __restrict__ Wih, const float* __restrict__ Whh,
    const float* __restrict__ bih, const float* __restrict__ bhh,
    float* __restrict__ out)
{
    __shared__ float h[kH];
    __shared__ float enc[kH];
    __shared__ float gbuf[768];

    const int b = blockIdx.x;
    const int tid = threadIdx.x;

    if (tid < kH) h[tid] = out[(size_t)b * kT * kH + tid];
    __syncthreads();

    if (tid < kH) {
        float s = fcb[tid];
        const float* row = fcW + (size_t)tid * kH;
#pragma unroll 4
        for (int k = 0; k < kH; k += 4) {
            const float4 v = *reinterpret_cast<const float4*>(row + k);
            s = fmaf(v.x, h[k + 0], s);
            s = fmaf(v.y, h[k + 1], s);
            s = fmaf(v.z, h[k + 2], s);
            s = fmaf(v.w, h[k + 3], s);
        }
        enc[tid] = s;
    }
    __syncthreads();

    for (int rr = 0; rr < 3; ++rr) {
        const int row = tid + 256 * rr;          // 0..767
        const float* Wr;
        const float* src;
        float s;
        if (row < 384) { Wr = Wih + (size_t)row * kH;        src = enc; s = bih[row]; }
        else           { Wr = Whh + (size_t)(row - 384) * kH; src = h;  s = bhh[row - 384]; }
#pragma unroll 4
        for (int k = 0; k < kH; k += 4) {
            const float4 v = *reinterpret_cast<const float4*>(Wr + k);
            s = fmaf(v.x, src[k + 0], s);
            s = fmaf(v.y, src[k + 1], s);
            s = fmaf(v.z, src[k + 2], s);
            s = fmaf(v.w, src[k + 3], s);
        }
        gbuf[row] = s;
    }
    __syncthreads();

    if (tid < kH) {
        const float r = fsigmoid(gbuf[tid] + gbuf[384 + tid]);
        const float z = fsigmoid(gbuf[128 + tid] + gbuf[512 + tid]);
        const float n = ftanh(gbuf[256 + tid] + r * gbuf[640 + tid]);
        out[((size_t)b * kT + 1) * kH + tid] = (1.0f - z) * n + z * h[tid];
    }
}

// ---------------- decoder (one block per batch element) ----------------
// 512 threads. quartet q = tid>>2 in [0,128); sub = tid&3 is the k-quarter.
// Per thread: 4 gate rows (r,z combined Wih+Whh; inn; hn) + out_W row quarter.
// k-chunk order rotated per sub so the 4 lanes hit disjoint LDS bank groups;
// rotation is applied at weight-LOAD time so weight indices stay static.
__global__ __launch_bounds__(512, 2) void dec_kernel(
    const float* __restrict__ Wih, const float* __restrict__ Whh,
    const float* __restrict__ bih, const float* __restrict__ bhh,
    const float* __restrict__ Wo,  const float* __restrict__ ob,
    float* __restrict__ out)
{
    __shared__ __align__(16) float hbuf[kH];
    __shared__ __align__(16) float obuf[kH];
    __shared__ int lastbad;

    const int b     = blockIdx.x;
    const int tid   = threadIdx.x;
    const int q     = tid >> 2;
    const int sub   = tid & 3;
    const int kbase = sub * 32;

    float w[4][32], wo[32];
#pragma unroll
    for (int cc = 0; cc < 8; ++cc) {
        const int kk = kbase + (((cc + 2 * sub) & 7) << 2);
        float4 vi, vh;
        vi = *reinterpret_cast<const float4*>(Wih + (size_t)q * kH + kk);
        vh = *reinterpret_cast<const float4*>(Whh + (size_t)q * kH + kk);
        ST4ADD(w[0], cc * 4, vi, vh);
        vi = *reinterpret_cast<const float4*>(Wih + (size_t)(kH + q) * kH + kk);
        vh = *reinterpret_cast<const float4*>(Whh + (size_t)(kH + q) * kH + kk);
        ST4ADD(w[1], cc * 4, vi, vh);
        vi = *reinterpret_cast<const float4*>(Wih + (size_t)(2 * kH + q) * kH + kk);
        ST4(w[2], cc * 4, vi);
        vh = *reinterpret_cast<const float4*>(Whh + (size_t)(2 * kH + q) * kH + kk);
        ST4(w[3], cc * 4, vh);
        const float4 vo = *reinterpret_cast<const float4*>(Wo + (size_t)q * kH + kk);
        ST4(wo, cc * 4, vo);
    }
    const float brz0 = bih[q] + bhh[q];
    const float brz1 = bih[kH + q] + bhh[kH + q];
    const float bin  = bih[2 * kH + q];
    const float bhn  = bhh[2 * kH + q];
    const float bo   = ob[q];

    if (tid < kH) hbuf[tid] = out[((size_t)b * kT + 1) * kH + tid];  // y0
    if (tid == 0) lastbad = -1;
    __syncthreads();

    float oval = 0.0f;
    int tfill = kT;
    for (int t = 0; t < kT; ++t) {
        float a0 = 0.f, a1 = 0.f, a2 = 0.f, a3 = 0.f, ao = 0.f;
#pragma unroll
        for (int cc = 0; cc < 8; ++cc) {
            const float4 v = *reinterpret_cast<const float4*>(
                hbuf + kbase + (((cc + 2 * sub) & 7) << 2));
            FMA4(a0, w[0], cc * 4);
            FMA4(a1, w[1], cc * 4);
            FMA4(a2, w[2], cc * 4);
            FMA4(a3, w[3], cc * 4);
            FMA4(ao, wo,   cc * 4);
        }
        a0 += __shfl_xor(a0, 1); a0 += __shfl_xor(a0, 2);
        a1 += __shfl_xor(a1, 1); a1 += __shfl_xor(a1, 2);
        a2 += __shfl_xor(a2, 1); a2 += __shfl_xor(a2, 2);
        a3 += __shfl_xor(a3, 1); a3 += __shfl_xor(a3, 2);
        ao += __shfl_xor(ao, 1); ao += __shfl_xor(ao, 2);

        const float hq = hbuf[q];
        oval = ao + bo;
        if (sub == 0) out[((size_t)b * kT + t) * kH + q] = oval;  // proj(h_t)
        if (t == kT - 1) break;

        const float r = fsigmoid(a0 + brz0);
        const float z = fsigmoid(a1 + brz1);
        const float n = ftanh(a2 + bin + r * (a3 + bhn));
        const float hnew = (1.0f - z) * n + z * hq;

        __syncthreads();              // all reads of hbuf done
        if (sub == 0) {
            hbuf[q] = hnew;
            if (!(hnew == hq)) lastbad = t;   // benign same-value race
        }
        __syncthreads();
        if (lastbad != t) { tfill = t + 1; break; }  // exact f32 fixed point
    }

    if (tfill < kT) {
        if (sub == 0) obuf[q] = oval;
        __syncthreads();
        const int l32 = tid & 31;
        const float4 ov = *reinterpret_cast<const float4*>(obuf + l32 * 4);
        for (int tt = tfill + (tid >> 5); tt < kT; tt += 16) {
            *reinterpret_cast<float4*>(out + ((size_t)b * kT + tt) * kH + l32 * 4) = ov;
        }
    }
}

}  // namespace

extern "C" void kernel_launch(void* const* d_in, const int* in_sizes, int n_in,
                              void* d_out, int out_size, void* d_ws, size_t ws_size,
                              hipStream_t stream) {
    (void)in_sizes; (void)n_in; (void)d_ws; (void)ws_size; (void)out_size;

    const float* to_x    = (const float*)d_in[0];
    const int*   lengths = (const int*)d_in[1];
    const float* eWih    = (const float*)d_in[2];
    const float* eWhh    = (const float*)d_in[3];
    const float* ebih    = (const float*)d_in[4];
    const float* ebhh    = (const float*)d_in[5];
    const float* fcW     = (const float*)d_in[6];
    const float* fcb     = (const float*)d_in[7];
    const float* dWih    = (const float*)d_in[8];
    const float* dWhh    = (const float*)d_in[9];
    const float* dbih    = (const float*)d_in[10];
    const float* dbhh    = (const float*)d_in[11];
    const float* oW      = (const float*)d_in[12];
    const float* obv     = (const float*)d_in[13];
    float* out = (float*)d_out;

    // h_enc staged in out[b][0][:], y0 in out[b][1][:] (consumed before overwrite)
    enc_kernel<<<64, 512, 0, stream>>>(to_x, lengths, eWih, eWhh, ebih, ebhh, out);
    y0_kernel<<<64, 256, 0, stream>>>(fcW, fcb, dWih, dWhh, dbih, dbhh, out);
    dec_kernel<<<64, 512, 0, stream>>>(dWih, dWhh, dbih, dbhh, oW, obv, out);
}

// Round 2
// 3501.314 us; speedup vs baseline: 1.2218x; 1.2218x over previous
//
#include <hip/hip_runtime.h>

namespace {

constexpr int kT = 2048;
constexpr int kH = 128;
constexpr int kB = 64;
constexpr int kG = 384;                      // 3H
constexpr size_t kM = (size_t)kB * kT;       // 131072 rows

__device__ __forceinline__ float fsigmoid(float x) {
    return 1.0f / (1.0f + __expf(-x));
}

__device__ __forceinline__ float ftanh(float x) {
    float xc = fminf(fmaxf(x, -15.0f), 15.0f);
    float e = __expf(2.0f * xc);
    return (e - 1.0f) / (e + 1.0f);
}

#define FMA4(acc, wrow, base)                      \
    acc = fmaf(v.x, wrow[(base) + 0], acc);        \
    acc = fmaf(v.y, wrow[(base) + 1], acc);        \
    acc = fmaf(v.z, wrow[(base) + 2], acc);        \
    acc = fmaf(v.w, wrow[(base) + 3], acc);

#define ST4(arr, base, vv)        \
    arr[(base) + 0] = (vv).x;     \
    arr[(base) + 1] = (vv).y;     \
    arr[(base) + 2] = (vv).z;     \
    arr[(base) + 3] = (vv).w;

#define ST4ADD(arr, base, va, vb)          \
    arr[(base) + 0] = (va).x + (vb).x;     \
    arr[(base) + 1] = (va).y + (vb).y;     \
    arr[(base) + 2] = (va).z + (vb).z;     \
    arr[(base) + 3] = (va).w + (vb).w;

// ================= gi precompute GEMM =================
// G[m][n] = bih[n] + dot(A[m][:], W[n][:]);  A=[131072][128], W=[384][128]
// grid (2048, 6), block 256. Tiles 64x64, K=128 full, k-major LDS.
__global__ __launch_bounds__(256, 2) void gi_gemm(
    const float* __restrict__ A, const float* __restrict__ W,
    const float* __restrict__ bias, float* __restrict__ G)
{
    __shared__ float As[128][68];
    __shared__ float Ws[128][68];
    const int m0 = blockIdx.x * 64;
    const int n0 = blockIdx.y * 64;
    const int tid = threadIdx.x;

#pragma unroll
    for (int jj = 0; jj < 8; ++jj) {
        const int i = tid + jj * 256;           // 0..2047
        const int r = i >> 5, cb = (i & 31) * 4;
        const float4 va = *reinterpret_cast<const float4*>(A + (size_t)(m0 + r) * kH + cb);
        As[cb + 0][r] = va.x; As[cb + 1][r] = va.y; As[cb + 2][r] = va.z; As[cb + 3][r] = va.w;
        const float4 vw = *reinterpret_cast<const float4*>(W + (size_t)(n0 + r) * kH + cb);
        Ws[cb + 0][r] = vw.x; Ws[cb + 1][r] = vw.y; Ws[cb + 2][r] = vw.z; Ws[cb + 3][r] = vw.w;
    }
    __syncthreads();

    const int tx = tid & 15, ty = tid >> 4;
    float acc[4][4] = {};
#pragma unroll 2
    for (int k = 0; k < 128; ++k) {
        const float4 a  = *reinterpret_cast<const float4*>(&As[k][ty * 4]);
        const float4 bv = *reinterpret_cast<const float4*>(&Ws[k][tx * 4]);
        const float av[4] = {a.x, a.y, a.z, a.w};
        const float bb[4] = {bv.x, bv.y, bv.z, bv.w};
#pragma unroll
        for (int r = 0; r < 4; ++r)
#pragma unroll
            for (int c = 0; c < 4; ++c) acc[r][c] = fmaf(av[r], bb[c], acc[r][c]);
    }
    const float4 b4 = *reinterpret_cast<const float4*>(bias + n0 + tx * 4);
    const float badd[4] = {b4.x, b4.y, b4.z, b4.w};
#pragma unroll
    for (int r = 0; r < 4; ++r) {
        float4 o;
        o.x = acc[r][0] + badd[0]; o.y = acc[r][1] + badd[1];
        o.z = acc[r][2] + badd[2]; o.w = acc[r][3] + badd[3];
        *reinterpret_cast<float4*>(G + (size_t)(m0 + ty * 4 + r) * kG + n0 + tx * 4) = o;
    }
}

// ================= encoder, gi-precomputed variant =================
// One block per batch element, 512 threads. Thread (j = tid>>2, sub = tid&3)
// does the 3 Whh gate dots over its k-quarter (rotated chunk order).
// Single barrier per step via double-buffered h and gi.
__global__ __launch_bounds__(512, 2) void enc_gi_kernel(
    const float* __restrict__ gi, const int* __restrict__ lengths,
    const float* __restrict__ Whh, const float* __restrict__ bhh,
    float* __restrict__ out)
{
    __shared__ __align__(16) float hb[2][128];
    __shared__ __align__(16) float gib[2][kG];

    const int b = blockIdx.x;
    const int tid = threadIdx.x;
    const int j = tid >> 2;
    const int sub = tid & 3;
    const int kbase = sub * 32;
    const int len = lengths[b];

    float w[3][32];
#pragma unroll
    for (int cc = 0; cc < 8; ++cc) {
        const int kk = kbase + (((cc + 2 * sub) & 7) << 2);
        float4 v;
        v = *reinterpret_cast<const float4*>(Whh + (size_t)j * kH + kk);            ST4(w[0], cc * 4, v);
        v = *reinterpret_cast<const float4*>(Whh + (size_t)(kH + j) * kH + kk);     ST4(w[1], cc * 4, v);
        v = *reinterpret_cast<const float4*>(Whh + (size_t)(2 * kH + j) * kH + kk); ST4(w[2], cc * 4, v);
    }
    const float bh0 = bhh[j];
    const float bh1 = bhh[kH + j];
    const float bh2 = bhh[2 * kH + j];

    if (tid < kH) hb[0][tid] = 0.0f;
    if (tid < 96) {
        const float4 g = *reinterpret_cast<const float4*>(gi + (size_t)b * kT * kG + tid * 4);
        *reinterpret_cast<float4*>(&gib[0][tid * 4]) = g;
    }
    __syncthreads();

    int cur = 0;
    for (int t = 0; t < len; ++t) {
        float4 gpre;
        const bool pl = (tid < 96) && (t + 1 < len);
        if (pl) {
            gpre = *reinterpret_cast<const float4*>(gi + ((size_t)b * kT + t + 1) * kG + tid * 4);
        }
        float a0 = 0.f, a1 = 0.f, a2 = 0.f;
#pragma unroll
        for (int cc = 0; cc < 8; ++cc) {
            const float4 v = *reinterpret_cast<const float4*>(
                &hb[cur][kbase + (((cc + 2 * sub) & 7) << 2)]);
            FMA4(a0, w[0], cc * 4);
            FMA4(a1, w[1], cc * 4);
            FMA4(a2, w[2], cc * 4);
        }
        a0 += __shfl_xor(a0, 1); a0 += __shfl_xor(a0, 2);
        a1 += __shfl_xor(a1, 1); a1 += __shfl_xor(a1, 2);
        a2 += __shfl_xor(a2, 1); a2 += __shfl_xor(a2, 2);

        const float gir = gib[cur][j];
        const float giz = gib[cur][kH + j];
        const float gin = gib[cur][2 * kH + j];
        const float hq  = hb[cur][j];

        const float r = fsigmoid(gir + a0 + bh0);
        const float z = fsigmoid(giz + a1 + bh1);
        const float n = ftanh(gin + r * (a2 + bh2));
        const float hnew = (1.0f - z) * n + z * hq;

        const int nxt = cur ^ 1;
        if (sub == 0) hb[nxt][j] = hnew;
        if (pl) *reinterpret_cast<float4*>(&gib[nxt][tid * 4]) = gpre;
        __syncthreads();
        cur = nxt;
    }
    if (tid < kH) out[((size_t)b * kT + 1) * kH + tid] = hb[cur][tid];  // h_enc stash
}

// ================= encoder, fallback (x-path in loop) =================
__global__ __launch_bounds__(512, 2) void enc_fb_kernel(
    const float* __restrict__ to_x, const int* __restrict__ lengths,
    const float* __restrict__ Wih, const float* __restrict__ Whh,
    const float* __restrict__ bih, const float* __restrict__ bhh,
    float* __restrict__ out)
{
    __shared__ __align__(16) float sm[2][264];  // x @ 0, h @ 132 (bank offset)
    const int b = blockIdx.x;
    const int tid = threadIdx.x;
    const int j = tid >> 2;
    const int s4 = tid & 3;
    const int xh = s4 >> 1;
    const int sub = s4 & 1;
    const int len = lengths[b];

    const float* W  = xh ? Whh : Wih;
    const float* bp = xh ? bhh : bih;

    float w[3][64];
#pragma unroll
    for (int r = 0; r < 3; ++r) {
        const float* rowp = W + (size_t)(r * kH + j) * kH + sub * 64;
#pragma unroll
        for (int k = 0; k < 64; k += 4) {
            const float4 v = *reinterpret_cast<const float4*>(rowp + k);
            ST4(w[r], k, v);
        }
    }
    const float bias0 = bp[j];
    const float bias1 = bp[kH + j];
    const float bias2 = bp[2 * kH + j];

    if (tid < kH) sm[0][132 + tid] = 0.0f;
    if (tid >= 128 && tid < 160) {
        const float4 v = *reinterpret_cast<const float4*>(
            to_x + (size_t)b * kT * kH + (tid - 128) * 4);
        *reinterpret_cast<float4*>(&sm[0][(tid - 128) * 4]) = v;
    }
    __syncthreads();

    int cur = 0;
    for (int t = 0; t < len; ++t) {
        float4 xf;
        const bool pl = (tid >= 480) && (t + 1 < len);
        if (pl) {
            xf = *reinterpret_cast<const float4*>(
                to_x + ((size_t)b * kT + t + 1) * kH + (tid - 480) * 4);
        }
        const float* src = sm[cur] + (xh ? 132 : 0) + sub * 64;
        float a0 = 0.f, a1 = 0.f, a2 = 0.f;
#pragma unroll
        for (int c = 0; c < 16; ++c) {
            const float4 v = *reinterpret_cast<const float4*>(src + c * 4);
            FMA4(a0, w[0], c * 4);
            FMA4(a1, w[1], c * 4);
            FMA4(a2, w[2], c * 4);
        }
        a0 += __shfl_xor(a0, 1);
        a1 += __shfl_xor(a1, 1);
        a2 += __shfl_xor(a2, 1);
        a0 += bias0; a1 += bias1; a2 += bias2;
        const float b0 = __shfl_xor(a0, 2);
        const float b1 = __shfl_xor(a1, 2);
        const float b2 = __shfl_xor(a2, 2);
        const float hq  = sm[cur][132 + j];
        const float r   = fsigmoid(a0 + b0);
        const float z   = fsigmoid(a1 + b1);
        const float inn = xh ? b2 : a2;
        const float hn  = xh ? a2 : b2;
        const float n   = ftanh(inn + r * hn);
        const float hnew = (1.0f - z) * n + z * hq;

        const int nxt = cur ^ 1;
        if (s4 == 0) sm[nxt][132 + j] = hnew;
        if (pl) *reinterpret_cast<float4*>(&sm[nxt][(tid - 480) * 4]) = xf;
        __syncthreads();
        cur = nxt;
    }
    if (tid < kH) out[((size_t)b * kT + 1) * kH + tid] = sm[cur][132 + tid];
}

// ================= fc + first decoder cell =================
// Reads h_enc from out row 1, writes y0 (= h_0) to out row 0.
__global__ void y0_kernel(
    const float* __restrict__ fcW, const float* __restrict__ fcb,
    const float* __restrict__ Wih, const float* __restrict__ Whh,
    const float* __restrict__ bih, const float* __restrict__ bhh,
    float* __restrict__ out)
{
    __shared__ float h[kH];
    __shared__ float enc[kH];
    __shared__ float gbuf[768];

    const int b = blockIdx.x;
    const int tid = threadIdx.x;

    if (tid < kH) h[tid] = out[((size_t)b * kT + 1) * kH + tid];
    __syncthreads();

    if (tid < kH) {
        float s = fcb[tid];
        const float* row = fcW + (size_t)tid * kH;
#pragma unroll 4
        for (int k = 0; k < kH; k += 4) {
            const float4 v = *reinterpret_cast<const float4*>(row + k);
            s = fmaf(v.x, h[k + 0], s);
            s = fmaf(v.y, h[k + 1], s);
            s = fmaf(v.z, h[k + 2], s);
            s = fmaf(v.w, h[k + 3], s);
        }
        enc[tid] = s;
    }
    __syncthreads();

    for (int rr = 0; rr < 3; ++rr) {
        const int row = tid + 256 * rr;          // 0..767
        const float* Wr;
        const float* src;
        float s;
        if (row < 384) { Wr = Wih + (size_t)row * kH;         src = enc; s = bih[row]; }
        else           { Wr = Whh + (size_t)(row - 384) * kH; src = h;   s = bhh[row - 384]; }
#pragma unroll 4
        for (int k = 0; k < kH; k += 4) {
            const float4 v = *reinterpret_cast<const float4*>(Wr + k);
            s = fmaf(v.x, src[k + 0], s);
            s = fmaf(v.y, src[k + 1], s);
            s = fmaf(v.z, src[k + 2], s);
            s = fmaf(v.w, src[k + 3], s);
        }
        gbuf[row] = s;
    }
    __syncthreads();

    if (tid < kH) {
        const float r = fsigmoid(gbuf[tid] + gbuf[384 + tid]);
        const float z = fsigmoid(gbuf[128 + tid] + gbuf[512 + tid]);
        const float n = ftanh(gbuf[256 + tid] + r * gbuf[640 + tid]);
        out[(size_t)b * kT * kH + tid] = (1.0f - z) * n + z * h[tid];
    }
}

// ================= decoder (stores h_t history; proj deferred) =================
__global__ __launch_bounds__(512, 2) void dec_kernel(
    const float* __restrict__ Wih, const float* __restrict__ Whh,
    const float* __restrict__ bih, const float* __restrict__ bhh,
    float* __restrict__ out)
{
    __shared__ __align__(16) float hb[2][128];

    const int b     = blockIdx.x;
    const int tid   = threadIdx.x;
    const int q     = tid >> 2;
    const int sub   = tid & 3;
    const int kbase = sub * 32;

    float w[4][32];
#pragma unroll
    for (int cc = 0; cc < 8; ++cc) {
        const int kk = kbase + (((cc + 2 * sub) & 7) << 2);
        float4 vi, vh;
        vi = *reinterpret_cast<const float4*>(Wih + (size_t)q * kH + kk);
        vh = *reinterpret_cast<const float4*>(Whh + (size_t)q * kH + kk);
        ST4ADD(w[0], cc * 4, vi, vh);
        vi = *reinterpret_cast<const float4*>(Wih + (size_t)(kH + q) * kH + kk);
        vh = *reinterpret_cast<const float4*>(Whh + (size_t)(kH + q) * kH + kk);
        ST4ADD(w[1], cc * 4, vi, vh);
        vi = *reinterpret_cast<const float4*>(Wih + (size_t)(2 * kH + q) * kH + kk);
        ST4(w[2], cc * 4, vi);
        vh = *reinterpret_cast<const float4*>(Whh + (size_t)(2 * kH + q) * kH + kk);
        ST4(w[3], cc * 4, vh);
    }
    const float brz0 = bih[q] + bhh[q];
    const float brz1 = bih[kH + q] + bhh[kH + q];
    const float bin  = bih[2 * kH + q];
    const float bhn  = bhh[2 * kH + q];

    if (tid < kH) hb[0][tid] = out[(size_t)b * kT * kH + tid];  // h_0 = y0
    __syncthreads();

    int cur = 0;
    for (int t = 1; t < kT; ++t) {
        float a0 = 0.f, a1 = 0.f, a2 = 0.f, a3 = 0.f;
#pragma unroll
        for (int cc = 0; cc < 8; ++cc) {
            const float4 v = *reinterpret_cast<const float4*>(
                &hb[cur][kbase + (((cc + 2 * sub) & 7) << 2)]);
            FMA4(a0, w[0], cc * 4);
            FMA4(a1, w[1], cc * 4);
            FMA4(a2, w[2], cc * 4);
            FMA4(a3, w[3], cc * 4);
        }
        a0 += __shfl_xor(a0, 1); a0 += __shfl_xor(a0, 2);
        a1 += __shfl_xor(a1, 1); a1 += __shfl_xor(a1, 2);
        a2 += __shfl_xor(a2, 1); a2 += __shfl_xor(a2, 2);
        a3 += __shfl_xor(a3, 1); a3 += __shfl_xor(a3, 2);

        const float hq = hb[cur][q];
        const float r = fsigmoid(a0 + brz0);
        const float z = fsigmoid(a1 + brz1);
        const float n = ftanh(a2 + bin + r * (a3 + bhn));
        const float hnew = (1.0f - z) * n + z * hq;

        const int nxt = cur ^ 1;
        if (sub == 0) {
            hb[nxt][q] = hnew;
            out[((size_t)b * kT + t) * kH + q] = hnew;   // h history (proj later)
        }
        __syncthreads();
        cur = nxt;
    }
}

// ================= in-place output projection =================
// out[m][o] = ob[o] + dot(h_m, Wo[o][:]) with h_m = current out row m.
// grid 2048, block 256; each block owns 64 full rows (in-place safe).
__global__ __launch_bounds__(256, 1) void proj_kernel(
    const float* __restrict__ Wo, const float* __restrict__ ob,
    float* __restrict__ out)
{
    __shared__ float As[128][68];    // k-major h tile
    __shared__ float Ws[128][132];   // k-major Wo
    const int m0 = blockIdx.x * 64;
    const int tid = threadIdx.x;

#pragma unroll
    for (int jj = 0; jj < 8; ++jj) {
        const int i = tid + jj * 256;           // 0..2047
        const int r = i >> 5, cb = (i & 31) * 4;
        const float4 v = *reinterpret_cast<const float4*>(out + (size_t)(m0 + r) * kH + cb);
        As[cb + 0][r] = v.x; As[cb + 1][r] = v.y; As[cb + 2][r] = v.z; As[cb + 3][r] = v.w;
    }
#pragma unroll
    for (int jj = 0; jj < 16; ++jj) {
        const int i = tid + jj * 256;           // 0..4095
        const int o = i >> 5, cb = (i & 31) * 4;
        const float4 v = *reinterpret_cast<const float4*>(Wo + (size_t)o * kH + cb);
        Ws[cb + 0][o] = v.x; Ws[cb + 1][o] = v.y; Ws[cb + 2][o] = v.z; Ws[cb + 3][o] = v.w;
    }
    __syncthreads();

    const int tx = tid & 15, ty = tid >> 4;
    float acc[4][8] = {};
#pragma unroll 2
    for (int k = 0; k < 128; ++k) {
        const float4 a  = *reinterpret_cast<const float4*>(&As[k][ty * 4]);
        const float4 b0 = *reinterpret_cast<const float4*>(&Ws[k][tx * 4]);
        const float4 b1 = *reinterpret_cast<const float4*>(&Ws[k][64 + tx * 4]);
        const float av[4] = {a.x, a.y, a.z, a.w};
        const float bb[8] = {b0.x, b0.y, b0.z, b0.w, b1.x, b1.y, b1.z, b1.w};
#pragma unroll
        for (int r = 0; r < 4; ++r)
#pragma unroll
            for (int c = 0; c < 8; ++c) acc[r][c] = fmaf(av[r], bb[c], acc[r][c]);
    }
    const float4 o0 = *reinterpret_cast<const float4*>(ob + tx * 4);
    const float4 o1 = *reinterpret_cast<const float4*>(ob + 64 + tx * 4);
    const float ba[8] = {o0.x, o0.y, o0.z, o0.w, o1.x, o1.y, o1.z, o1.w};
#pragma unroll
    for (int r = 0; r < 4; ++r) {
        float4 s0, s1;
        s0.x = acc[r][0] + ba[0]; s0.y = acc[r][1] + ba[1];
        s0.z = acc[r][2] + ba[2]; s0.w = acc[r][3] + ba[3];
        s1.x = acc[r][4] + ba[4]; s1.y = acc[r][5] + ba[5];
        s1.z = acc[r][6] + ba[6]; s1.w = acc[r][7] + ba[7];
        float* rowp = out + (size_t)(m0 + ty * 4 + r) * kH;
        *reinterpret_cast<float4*>(rowp + tx * 4)      = s0;
        *reinterpret_cast<float4*>(rowp + 64 + tx * 4) = s1;
    }
}

}  // namespace

extern "C" void kernel_launch(void* const* d_in, const int* in_sizes, int n_in,
                              void* d_out, int out_size, void* d_ws, size_t ws_size,
                              hipStream_t stream) {
    (void)in_sizes; (void)n_in; (void)out_size;

    const float* to_x    = (const float*)d_in[0];
    const int*   lengths = (const int*)d_in[1];
    const float* eWih    = (const float*)d_in[2];
    const float* eWhh    = (const float*)d_in[3];
    const float* ebih    = (const float*)d_in[4];
    const float* ebhh    = (const float*)d_in[5];
    const float* fcW     = (const float*)d_in[6];
    const float* fcb     = (const float*)d_in[7];
    const float* dWih    = (const float*)d_in[8];
    const float* dWhh    = (const float*)d_in[9];
    const float* dbih    = (const float*)d_in[10];
    const float* dbhh    = (const float*)d_in[11];
    const float* oW      = (const float*)d_in[12];
    const float* obv     = (const float*)d_in[13];
    float* out = (float*)d_out;

    const size_t gi_bytes = kM * (size_t)kG * sizeof(float);   // ~201 MB
    if (ws_size >= gi_bytes) {
        float* gi = (float*)d_ws;
        gi_gemm<<<dim3(2048, 6), 256, 0, stream>>>(to_x, eWih, ebih, gi);
        enc_gi_kernel<<<kB, 512, 0, stream>>>(gi, lengths, eWhh, ebhh, out);
    } else {
        enc_fb_kernel<<<kB, 512, 0, stream>>>(to_x, lengths, eWih, eWhh, ebih, ebhh, out);
    }
    y0_kernel<<<kB, 256, 0, stream>>>(fcW, fcb, dWih, dWhh, dbih, dbhh, out);
    dec_kernel<<<kB, 512, 0, stream>>>(dWih, dWhh, dbih, dbhh, out);
    proj_kernel<<<2048, 256, 0, stream>>>(oW, obv, out);
}

// Round 3
// 3336.311 us; speedup vs baseline: 1.2823x; 1.0495x over previous
//
#include <hip/hip_runtime.h>

namespace {

constexpr int kT = 2048;
constexpr int kH = 128;
constexpr int kB = 64;
constexpr int kG = 384;                      // 3H
constexpr size_t kM = (size_t)kB * kT;       // 131072 rows

__device__ __forceinline__ float fsigmoid(float x) {
    return 1.0f / (1.0f + __expf(-x));
}

__device__ __forceinline__ float ftanh(float x) {
    float xc = fminf(fmaxf(x, -15.0f), 15.0f);
    float e = __expf(2.0f * xc);
    return (e - 1.0f) / (e + 1.0f);
}

#define FMA4(acc, wrow, base)                      \
    acc = fmaf(v.x, wrow[(base) + 0], acc);        \
    acc = fmaf(v.y, wrow[(base) + 1], acc);        \
    acc = fmaf(v.z, wrow[(base) + 2], acc);        \
    acc = fmaf(v.w, wrow[(base) + 3], acc);

#define ST4(arr, base, vv)        \
    arr[(base) + 0] = (vv).x;     \
    arr[(base) + 1] = (vv).y;     \
    arr[(base) + 2] = (vv).z;     \
    arr[(base) + 3] = (vv).w;

#define ST4ADD(arr, base, va, vb)          \
    arr[(base) + 0] = (va).x + (vb).x;     \
    arr[(base) + 1] = (va).y + (vb).y;     \
    arr[(base) + 2] = (va).z + (vb).z;     \
    arr[(base) + 3] = (va).w + (vb).w;

// ================= gi precompute GEMM =================
// G[m][n] = bih[n] + dot(A[m][:], W[n][:]);  A=[131072][128], W=[384][128]
// 12288 linear blocks, XCD-aware mapping: lin%8 = XCD slot; within an XCD,
// 6 consecutive n-tiles share one m-tile -> A tile fetched once per XCD L2.
__global__ __launch_bounds__(256, 2) void gi_gemm(
    const float* __restrict__ A, const float* __restrict__ W,
    const float* __restrict__ bias, float* __restrict__ G)
{
    __shared__ float As[128][68];
    __shared__ float Ws[128][68];
    const int lin = blockIdx.x;          // 0..12287
    const int xcd = lin & 7;
    const int kk  = lin >> 3;            // 0..1535
    const int m0  = (xcd * 256 + (kk / 6)) * 64;
    const int n0  = (kk % 6) * 64;
    const int tid = threadIdx.x;

#pragma unroll
    for (int jj = 0; jj < 8; ++jj) {
        const int i = tid + jj * 256;           // 0..2047
        const int r = i >> 5, cb = (i & 31) * 4;
        const float4 va = *reinterpret_cast<const float4*>(A + (size_t)(m0 + r) * kH + cb);
        As[cb + 0][r] = va.x; As[cb + 1][r] = va.y; As[cb + 2][r] = va.z; As[cb + 3][r] = va.w;
        const float4 vw = *reinterpret_cast<const float4*>(W + (size_t)(n0 + r) * kH + cb);
        Ws[cb + 0][r] = vw.x; Ws[cb + 1][r] = vw.y; Ws[cb + 2][r] = vw.z; Ws[cb + 3][r] = vw.w;
    }
    __syncthreads();

    const int tx = tid & 15, ty = tid >> 4;
    float acc[4][4] = {};
#pragma unroll 2
    for (int k = 0; k < 128; ++k) {
        const float4 a  = *reinterpret_cast<const float4*>(&As[k][ty * 4]);
        const float4 bv = *reinterpret_cast<const float4*>(&Ws[k][tx * 4]);
        const float av[4] = {a.x, a.y, a.z, a.w};
        const float bb[4] = {bv.x, bv.y, bv.z, bv.w};
#pragma unroll
        for (int r = 0; r < 4; ++r)
#pragma unroll
            for (int c = 0; c < 4; ++c) acc[r][c] = fmaf(av[r], bb[c], acc[r][c]);
    }
    const float4 b4 = *reinterpret_cast<const float4*>(bias + n0 + tx * 4);
    const float badd[4] = {b4.x, b4.y, b4.z, b4.w};
#pragma unroll
    for (int r = 0; r < 4; ++r) {
        float4 o;
        o.x = acc[r][0] + badd[0]; o.y = acc[r][1] + badd[1];
        o.z = acc[r][2] + badd[2]; o.w = acc[r][3] + badd[3];
        *reinterpret_cast<float4*>(G + (size_t)(m0 + ty * 4 + r) * kG + n0 + tx * 4) = o;
    }
}

// ================= encoder, gi-precomputed variant =================
// One block per batch element, 512 threads. Thread (j = tid>>2, sub = tid&3)
// does the 3 Whh gate dots over its k-quarter. gi values loaded per-thread
// directly into a 4-deep register ring (no LDS staging, latency off critical
// path). Loop bound rounded to 4; steps >= len freeze h (packed-seq exact).
__global__ __launch_bounds__(512, 2) void enc_gi_kernel(
    const float* __restrict__ gi, const int* __restrict__ lengths,
    const float* __restrict__ Whh, const float* __restrict__ bhh,
    float* __restrict__ out)
{
    __shared__ __align__(16) float hb[2][128];

    const int b = blockIdx.x;
    const int tid = threadIdx.x;
    const int j = tid >> 2;
    const int sub = tid & 3;
    const int kbase = sub * 32;
    const int len = lengths[b];

    float w[3][32];
#pragma unroll
    for (int cc = 0; cc < 8; ++cc) {
        const int kk = kbase + (((cc + 2 * sub) & 7) << 2);
        float4 v;
        v = *reinterpret_cast<const float4*>(Whh + (size_t)j * kH + kk);            ST4(w[0], cc * 4, v);
        v = *reinterpret_cast<const float4*>(Whh + (size_t)(kH + j) * kH + kk);     ST4(w[1], cc * 4, v);
        v = *reinterpret_cast<const float4*>(Whh + (size_t)(2 * kH + j) * kH + kk); ST4(w[2], cc * 4, v);
    }
    const float bh0 = bhh[j];
    const float bh1 = bhh[kH + j];
    const float bh2 = bhh[2 * kH + j];

    const float* gbase = gi + (size_t)b * kT * kG;
    float gr[4], gz[4], gn[4];
#define LOADG(s, tt)                                              \
    do {                                                          \
        const int tc = ((tt) < len) ? (tt) : (len - 1);           \
        const float* gp = gbase + (size_t)tc * kG;                \
        gr[s] = gp[j]; gz[s] = gp[kH + j]; gn[s] = gp[2 * kH + j];\
    } while (0)
    LOADG(0, 0); LOADG(1, 1); LOADG(2, 2); LOADG(3, 3);

    if (tid < kH) hb[0][tid] = 0.0f;
    __syncthreads();

    int cur = 0;
    const int lenUp = (len + 3) & ~3;

#define ENC_STEP(s)                                                        \
    do {                                                                   \
        const int t = t0 + (s);                                            \
        float a0 = 0.f, a1 = 0.f, a2 = 0.f;                                \
        _Pragma("unroll")                                                  \
        for (int cc = 0; cc < 8; ++cc) {                                   \
            const float4 v = *reinterpret_cast<const float4*>(             \
                &hb[cur][kbase + (((cc + 2 * sub) & 7) << 2)]);            \
            FMA4(a0, w[0], cc * 4);                                        \
            FMA4(a1, w[1], cc * 4);                                        \
            FMA4(a2, w[2], cc * 4);                                        \
        }                                                                  \
        a0 += __shfl_xor(a0, 1); a0 += __shfl_xor(a0, 2);                  \
        a1 += __shfl_xor(a1, 1); a1 += __shfl_xor(a1, 2);                  \
        a2 += __shfl_xor(a2, 1); a2 += __shfl_xor(a2, 2);                  \
        const float hq = hb[cur][j];                                       \
        const float r = fsigmoid(gr[s] + a0 + bh0);                        \
        const float z = fsigmoid(gz[s] + a1 + bh1);                        \
        const float n = ftanh(gn[s] + r * (a2 + bh2));                     \
        const float hnew = (1.0f - z) * n + z * hq;                        \
        const float hc = (t < len) ? hnew : hq;                            \
        LOADG(s, t + 4);                                                   \
        const int nxt = cur ^ 1;                                           \
        if (sub == 0) hb[nxt][j] = hc;                                     \
        __syncthreads();                                                   \
        cur = nxt;                                                         \
    } while (0)

    for (int t0 = 0; t0 < lenUp; t0 += 4) {
        ENC_STEP(0); ENC_STEP(1); ENC_STEP(2); ENC_STEP(3);
    }
#undef ENC_STEP
#undef LOADG

    if (tid < kH) out[((size_t)b * kT + 1) * kH + tid] = hb[cur][tid];  // h_enc stash
}

// ================= encoder, fallback (x-path in loop) =================
// Same structure as round 2 but x prefetched 4 steps ahead through a float4
// register ring on loader lanes (tid>=480) into a 4-deep LDS ring.
__global__ __launch_bounds__(512, 2) void enc_fb_kernel(
    const float* __restrict__ to_x, const int* __restrict__ lengths,
    const float* __restrict__ Wih, const float* __restrict__ Whh,
    const float* __restrict__ bih, const float* __restrict__ bhh,
    float* __restrict__ out)
{
    __shared__ __align__(16) float hb2[2][132];
    __shared__ __align__(16) float xr[4][132];

    const int b = blockIdx.x;
    const int tid = threadIdx.x;
    const int j = tid >> 2;
    const int s4 = tid & 3;
    const int xh = s4 >> 1;
    const int sub = s4 & 1;
    const int len = lengths[b];
    const bool loader = (tid >= 480);
    const float* xrow = to_x + (size_t)b * kT * kH + (tid - 480) * 4;

    const float* W  = xh ? Whh : Wih;
    const float* bp = xh ? bhh : bih;

    float w[3][64];
#pragma unroll
    for (int r = 0; r < 3; ++r) {
        const float* rowp = W + (size_t)(r * kH + j) * kH + sub * 64;
#pragma unroll
        for (int k = 0; k < 64; k += 4) {
            const float4 v = *reinterpret_cast<const float4*>(rowp + k);
            ST4(w[r], k, v);
        }
    }
    const float bias0 = bp[j];
    const float bias1 = bp[kH + j];
    const float bias2 = bp[2 * kH + j];

    float4 xf0, xf1, xf2, xf3;
    if (tid < kH) hb2[0][tid] = 0.0f;
    if (loader) {
        xf0 = *reinterpret_cast<const float4*>(xrow + 0 * (size_t)kH);
        xf1 = *reinterpret_cast<const float4*>(xrow + 1 * (size_t)kH);
        xf2 = *reinterpret_cast<const float4*>(xrow + 2 * (size_t)kH);
        xf3 = *reinterpret_cast<const float4*>(xrow + 3 * (size_t)kH);
        *reinterpret_cast<float4*>(&xr[0][(tid - 480) * 4]) = xf0;
    }
    __syncthreads();

    int cur = 0;
    const int lenUp = (len + 3) & ~3;

#define FB_STEP(s, XFCUR, XFNEXT)                                          \
    do {                                                                   \
        const int t = t0 + (s);                                            \
        const float* src = (xh ? &hb2[cur][0] : &xr[s][0]) + sub * 64;     \
        float a0 = 0.f, a1 = 0.f, a2 = 0.f;                                \
        _Pragma("unroll")                                                  \
        for (int c = 0; c < 16; ++c) {                                     \
            const float4 v = *reinterpret_cast<const float4*>(src + c * 4);\
            FMA4(a0, w[0], c * 4);                                         \
            FMA4(a1, w[1], c * 4);                                         \
            FMA4(a2, w[2], c * 4);                                         \
        }                                                                  \
        a0 += __shfl_xor(a0, 1);                                           \
        a1 += __shfl_xor(a1, 1);                                           \
        a2 += __shfl_xor(a2, 1);                                           \
        a0 += bias0; a1 += bias1; a2 += bias2;                             \
        const float b0 = __shfl_xor(a0, 2);                                \
        const float b1 = __shfl_xor(a1, 2);                                \
        const float b2 = __shfl_xor(a2, 2);                                \
        const float hq  = hb2[cur][j];                                     \
        const float r   = fsigmoid(a0 + b0);                               \
        const float z   = fsigmoid(a1 + b1);                               \
        const float inn = xh ? b2 : a2;                                    \
        const float hn  = xh ? a2 : b2;                                    \
        const float n   = ftanh(inn + r * hn);                             \
        const float hnew = (1.0f - z) * n + z * hq;                        \
        const float hc = (t < len) ? hnew : hq;                            \
        if (loader) {                                                      \
            const int tc = ((t + 4) < len) ? (t + 4) : (len - 1);          \
            XFCUR = *reinterpret_cast<const float4*>(xrow + (size_t)tc * kH); \
        }                                                                  \
        const int nxt = cur ^ 1;                                           \
        if (s4 == 0) hb2[nxt][j] = hc;                                     \
        if (loader) *reinterpret_cast<float4*>(&xr[((s) + 1) & 3][(tid - 480) * 4]) = XFNEXT; \
        __syncthreads();                                                   \
        cur = nxt;                                                         \
    } while (0)

    for (int t0 = 0; t0 < lenUp; t0 += 4) {
        FB_STEP(0, xf0, xf1);
        FB_STEP(1, xf1, xf2);
        FB_STEP(2, xf2, xf3);
        FB_STEP(3, xf3, xf0);
    }
#undef FB_STEP

    if (tid < kH) out[((size_t)b * kT + 1) * kH + tid] = hb2[cur][tid];
}

// ================= fc + first decoder cell =================
// Reads h_enc from out row 1, writes y0 (= h_0) to out row 0.
__global__ void y0_kernel(
    const float* __restrict__ fcW, const float* __restrict__ fcb,
    const float* __restrict__ Wih, const float* __restrict__ Whh,
    const float* __restrict__ bih, const float* __restrict__ bhh,
    float* __restrict__ out)
{
    __shared__ float h[kH];
    __shared__ float enc[kH];
    __shared__ float gbuf[768];

    const int b = blockIdx.x;
    const int tid = threadIdx.x;

    if (tid < kH) h[tid] = out[((size_t)b * kT + 1) * kH + tid];
    __syncthreads();

    if (tid < kH) {
        float s = fcb[tid];
        const float* row = fcW + (size_t)tid * kH;
#pragma unroll 4
        for (int k = 0; k < kH; k += 4) {
            const float4 v = *reinterpret_cast<const float4*>(row + k);
            s = fmaf(v.x, h[k + 0], s);
            s = fmaf(v.y, h[k + 1], s);
            s = fmaf(v.z, h[k + 2], s);
            s = fmaf(v.w, h[k + 3], s);
        }
        enc[tid] = s;
    }
    __syncthreads();

    for (int rr = 0; rr < 3; ++rr) {
        const int row = tid + 256 * rr;          // 0..767
        const float* Wr;
        const float* src;
        float s;
        if (row < 384) { Wr = Wih + (size_t)row * kH;         src = enc; s = bih[row]; }
        else           { Wr = Whh + (size_t)(row - 384) * kH; src = h;   s = bhh[row - 384]; }
#pragma unroll 4
        for (int k = 0; k < kH; k += 4) {
            const float4 v = *reinterpret_cast<const float4*>(Wr + k);
            s = fmaf(v.x, src[k + 0], s);
            s = fmaf(v.y, src[k + 1], s);
            s = fmaf(v.z, src[k + 2], s);
            s = fmaf(v.w, src[k + 3], s);
        }
        gbuf[row] = s;
    }
    __syncthreads();

    if (tid < kH) {
        const float r = fsigmoid(gbuf[tid] + gbuf[384 + tid]);
        const float z = fsigmoid(gbuf[128 + tid] + gbuf[512 + tid]);
        const float n = ftanh(gbuf[256 + tid] + r * gbuf[640 + tid]);
        out[(size_t)b * kT * kH + tid] = (1.0f - z) * n + z * h[tid];
    }
}

// ================= decoder (stores h_t history; proj deferred) =================
__global__ __launch_bounds__(512, 2) void dec_kernel(
    const float* __restrict__ Wih, const float* __restrict__ Whh,
    const float* __restrict__ bih, const float* __restrict__ bhh,
    float* __restrict__ out)
{
    __shared__ __align__(16) float hb[2][128];

    const int b     = blockIdx.x;
    const int tid   = threadIdx.x;
    const int q     = tid >> 2;
    const int sub   = tid & 3;
    const int kbase = sub * 32;

    float w[4][32];
#pragma unroll
    for (int cc = 0; cc < 8; ++cc) {
        const int kk = kbase + (((cc + 2 * sub) & 7) << 2);
        float4 vi, vh;
        vi = *reinterpret_cast<const float4*>(Wih + (size_t)q * kH + kk);
        vh = *reinterpret_cast<const float4*>(Whh + (size_t)q * kH + kk);
        ST4ADD(w[0], cc * 4, vi, vh);
        vi = *reinterpret_cast<const float4*>(Wih + (size_t)(kH + q) * kH + kk);
        vh = *reinterpret_cast<const float4*>(Whh + (size_t)(kH + q) * kH + kk);
        ST4ADD(w[1], cc * 4, vi, vh);
        vi = *reinterpret_cast<const float4*>(Wih + (size_t)(2 * kH + q) * kH + kk);
        ST4(w[2], cc * 4, vi);
        vh = *reinterpret_cast<const float4*>(Whh + (size_t)(2 * kH + q) * kH + kk);
        ST4(w[3], cc * 4, vh);
    }
    const float brz0 = bih[q] + bhh[q];
    const float brz1 = bih[kH + q] + bhh[kH + q];
    const float bin  = bih[2 * kH + q];
    const float bhn  = bhh[2 * kH + q];

    if (tid < kH) hb[0][tid] = out[(size_t)b * kT * kH + tid];  // h_0 = y0
    __syncthreads();

    int cur = 0;
    for (int t = 1; t < kT; ++t) {
        float a0 = 0.f, a1 = 0.f, a2 = 0.f, a3 = 0.f;
#pragma unroll
        for (int cc = 0; cc < 8; ++cc) {
            const float4 v = *reinterpret_cast<const float4*>(
                &hb[cur][kbase + (((cc + 2 * sub) & 7) << 2)]);
            FMA4(a0, w[0], cc * 4);
            FMA4(a1, w[1], cc * 4);
            FMA4(a2, w[2], cc * 4);
            FMA4(a3, w[3], cc * 4);
        }
        a0 += __shfl_xor(a0, 1); a0 += __shfl_xor(a0, 2);
        a1 += __shfl_xor(a1, 1); a1 += __shfl_xor(a1, 2);
        a2 += __shfl_xor(a2, 1); a2 += __shfl_xor(a2, 2);
        a3 += __shfl_xor(a3, 1); a3 += __shfl_xor(a3, 2);

        const float hq = hb[cur][q];
        const float r = fsigmoid(a0 + brz0);
        const float z = fsigmoid(a1 + brz1);
        const float n = ftanh(a2 + bin + r * (a3 + bhn));
        const float hnew = (1.0f - z) * n + z * hq;

        const int nxt = cur ^ 1;
        if (sub == 0) {
            hb[nxt][q] = hnew;
            out[((size_t)b * kT + t) * kH + q] = hnew;   // h history (proj later)
        }
        __syncthreads();
        cur = nxt;
    }
}

// ================= in-place output projection =================
__global__ __launch_bounds__(256, 1) void proj_kernel(
    const float* __restrict__ Wo, const float* __restrict__ ob,
    float* __restrict__ out)
{
    __shared__ float As[128][68];    // k-major h tile
    __shared__ float Ws[128][132];   // k-major Wo
    const int m0 = blockIdx.x * 64;
    const int tid = threadIdx.x;

#pragma unroll
    for (int jj = 0; jj < 8; ++jj) {
        const int i = tid + jj * 256;           // 0..2047
        const int r = i >> 5, cb = (i & 31) * 4;
        const float4 v = *reinterpret_cast<const float4*>(out + (size_t)(m0 + r) * kH + cb);
        As[cb + 0][r] = v.x; As[cb + 1][r] = v.y; As[cb + 2][r] = v.z; As[cb + 3][r] = v.w;
    }
#pragma unroll
    for (int jj = 0; jj < 16; ++jj) {
        const int i = tid + jj * 256;           // 0..4095
        const int o = i >> 5, cb = (i & 31) * 4;
        const float4 v = *reinterpret_cast<const float4*>(Wo + (size_t)o * kH + cb);
        Ws[cb + 0][o] = v.x; Ws[cb + 1][o] = v.y; Ws[cb + 2][o] = v.z; Ws[cb + 3][o] = v.w;
    }
    __syncthreads();

    const int tx = tid & 15, ty = tid >> 4;
    float acc[4][8] = {};
#pragma unroll 2
    for (int k = 0; k < 128; ++k) {
        const float4 a  = *reinterpret_cast<const float4*>(&As[k][ty * 4]);
        const float4 b0 = *reinterpret_cast<const float4*>(&Ws[k][tx * 4]);
        const float4 b1 = *reinterpret_cast<const float4*>(&Ws[k][64 + tx * 4]);
        const float av[4] = {a.x, a.y, a.z, a.w};
        const float bb[8] = {b0.x, b0.y, b0.z, b0.w, b1.x, b1.y, b1.z, b1.w};
#pragma unroll
        for (int r = 0; r < 4; ++r)
#pragma unroll
            for (int c = 0; c < 8; ++c) acc[r][c] = fmaf(av[r], bb[c], acc[r][c]);
    }
    const float4 o0 = *reinterpret_cast<const float4*>(ob + tx * 4);
    const float4 o1 = *reinterpret_cast<const float4*>(ob + 64 + tx * 4);
    const float ba[8] = {o0.x, o0.y, o0.z, o0.w, o1.x, o1.y, o1.z, o1.w};
#pragma unroll
    for (int r = 0; r < 4; ++r) {
        float4 s0, s1;
        s0.x = acc[r][0] + ba[0]; s0.y = acc[r][1] + ba[1];
        s0.z = acc[r][2] + ba[2]; s0.w = acc[r][3] + ba[3];
        s1.x = acc[r][4] + ba[4]; s1.y = acc[r][5] + ba[5];
        s1.z = acc[r][6] + ba[6]; s1.w = acc[r][7] + ba[7];
        float* rowp = out + (size_t)(m0 + ty * 4 + r) * kH;
        *reinterpret_cast<float4*>(rowp + tx * 4)      = s0;
        *reinterpret_cast<float4*>(rowp + 64 + tx * 4) = s1;
    }
}

}  // namespace

extern "C" void kernel_launch(void* const* d_in, const int* in_sizes, int n_in,
                              void* d_out, int out_size, void* d_ws, size_t ws_size,
                              hipStream_t stream) {
    (void)in_sizes; (void)n_in; (void)out_size;

    const float* to_x    = (const float*)d_in[0];
    const int*   lengths = (const int*)d_in[1];
    const float* eWih    = (const float*)d_in[2];
    const float* eWhh    = (const float*)d_in[3];
    const float* ebih    = (const float*)d_in[4];
    const float* ebhh    = (const float*)d_in[5];
    const float* fcW     = (const float*)d_in[6];
    const float* fcb     = (const float*)d_in[7];
    const float* dWih    = (const float*)d_in[8];
    const float* dWhh    = (const float*)d_in[9];
    const float* dbih    = (const float*)d_in[10];
    const float* dbhh    = (const float*)d_in[11];
    const float* oW      = (const float*)d_in[12];
    const float* obv     = (const float*)d_in[13];
    float* out = (float*)d_out;

    const size_t gi_bytes = kM * (size_t)kG * sizeof(float);   // ~201 MB
    if (ws_size >= gi_bytes) {
        float* gi = (float*)d_ws;
        gi_gemm<<<12288, 256, 0, stream>>>(to_x, eWih, ebih, gi);
        enc_gi_kernel<<<kB, 512, 0, stream>>>(gi, lengths, eWhh, ebhh, out);
    } else {
        enc_fb_kernel<<<kB, 512, 0, stream>>>(to_x, lengths, eWih, eWhh, ebih, ebhh, out);
    }
    y0_kernel<<<kB, 256, 0, stream>>>(fcW, fcb, dWih, dWhh, dbih, dbhh, out);
    dec_kernel<<<kB, 512, 0, stream>>>(dWih, dWhh, dbih, dbhh, out);
    proj_kernel<<<2048, 256, 0, stream>>>(oW, obv, out);
}

// Round 4
// 3305.634 us; speedup vs baseline: 1.2942x; 1.0093x over previous
//
#include <hip/hip_runtime.h>

namespace {

constexpr int kT = 2048;
constexpr int kH = 128;
constexpr int kB = 64;
constexpr int kG = 384;                      // 3H
constexpr size_t kM = (size_t)kB * kT;       // 131072 rows

__device__ __forceinline__ float fsigmoid(float x) {
    return 1.0f / (1.0f + __expf(-x));
}

__device__ __forceinline__ float ftanh(float x) {
    float xc = fminf(fmaxf(x, -15.0f), 15.0f);
    float e = __expf(2.0f * xc);
    return (e - 1.0f) / (e + 1.0f);
}

// LDS-only barrier: does NOT drain vmcnt, so global loads/stores stay in
// flight across steps (T4 counted-vmcnt philosophy). __syncthreads() would
// emit s_waitcnt vmcnt(0) before s_barrier and serialize HBM latency into
// every recurrence step (m97 finding).
__device__ __forceinline__ void lds_barrier() {
    __builtin_amdgcn_sched_barrier(0);
    asm volatile("s_waitcnt lgkmcnt(0)" ::: "memory");
    __builtin_amdgcn_s_barrier();
    __builtin_amdgcn_sched_barrier(0);
}

#define FMA4(acc, wrow, base)                      \
    acc = fmaf(v.x, wrow[(base) + 0], acc);        \
    acc = fmaf(v.y, wrow[(base) + 1], acc);        \
    acc = fmaf(v.z, wrow[(base) + 2], acc);        \
    acc = fmaf(v.w, wrow[(base) + 3], acc);

#define ST4(arr, base, vv)        \
    arr[(base) + 0] = (vv).x;     \
    arr[(base) + 1] = (vv).y;     \
    arr[(base) + 2] = (vv).z;     \
    arr[(base) + 3] = (vv).w;

#define ST4ADD(arr, base, va, vb)          \
    arr[(base) + 0] = (va).x + (vb).x;     \
    arr[(base) + 1] = (va).y + (vb).y;     \
    arr[(base) + 2] = (va).z + (vb).z;     \
    arr[(base) + 3] = (va).w + (vb).w;

// ================= gi precompute GEMM =================
__global__ __launch_bounds__(256, 2) void gi_gemm(
    const float* __restrict__ A, const float* __restrict__ W,
    const float* __restrict__ bias, float* __restrict__ G)
{
    __shared__ float As[128][68];
    __shared__ float Ws[128][68];
    const int lin = blockIdx.x;          // 0..12287
    const int xcd = lin & 7;
    const int kk  = lin >> 3;            // 0..1535
    const int m0  = (xcd * 256 + (kk / 6)) * 64;
    const int n0  = (kk % 6) * 64;
    const int tid = threadIdx.x;

#pragma unroll
    for (int jj = 0; jj < 8; ++jj) {
        const int i = tid + jj * 256;           // 0..2047
        const int r = i >> 5, cb = (i & 31) * 4;
        const float4 va = *reinterpret_cast<const float4*>(A + (size_t)(m0 + r) * kH + cb);
        As[cb + 0][r] = va.x; As[cb + 1][r] = va.y; As[cb + 2][r] = va.z; As[cb + 3][r] = va.w;
        const float4 vw = *reinterpret_cast<const float4*>(W + (size_t)(n0 + r) * kH + cb);
        Ws[cb + 0][r] = vw.x; Ws[cb + 1][r] = vw.y; Ws[cb + 2][r] = vw.z; Ws[cb + 3][r] = vw.w;
    }
    __syncthreads();

    const int tx = tid & 15, ty = tid >> 4;
    float acc[4][4] = {};
#pragma unroll 2
    for (int k = 0; k < 128; ++k) {
        const float4 a  = *reinterpret_cast<const float4*>(&As[k][ty * 4]);
        const float4 bv = *reinterpret_cast<const float4*>(&Ws[k][tx * 4]);
        const float av[4] = {a.x, a.y, a.z, a.w};
        const float bb[4] = {bv.x, bv.y, bv.z, bv.w};
#pragma unroll
        for (int r = 0; r < 4; ++r)
#pragma unroll
            for (int c = 0; c < 4; ++c) acc[r][c] = fmaf(av[r], bb[c], acc[r][c]);
    }
    const float4 b4 = *reinterpret_cast<const float4*>(bias + n0 + tx * 4);
    const float badd[4] = {b4.x, b4.y, b4.z, b4.w};
#pragma unroll
    for (int r = 0; r < 4; ++r) {
        float4 o;
        o.x = acc[r][0] + badd[0]; o.y = acc[r][1] + badd[1];
        o.z = acc[r][2] + badd[2]; o.w = acc[r][3] + badd[3];
        *reinterpret_cast<float4*>(G + (size_t)(m0 + ty * 4 + r) * kG + n0 + tx * 4) = o;
    }
}

// ================= encoder, gi-precomputed variant =================
__global__ __launch_bounds__(512, 2) void enc_gi_kernel(
    const float* __restrict__ gi, const int* __restrict__ lengths,
    const float* __restrict__ Whh, const float* __restrict__ bhh,
    float* __restrict__ out)
{
    __shared__ __align__(16) float hb[2][128];

    const int b = blockIdx.x;
    const int tid = threadIdx.x;
    const int j = tid >> 2;
    const int sub = tid & 3;
    const int kbase = sub * 32;
    const int len = lengths[b];

    float w[3][32];
#pragma unroll
    for (int cc = 0; cc < 8; ++cc) {
        const int kk = kbase + (((cc + 2 * sub) & 7) << 2);
        float4 v;
        v = *reinterpret_cast<const float4*>(Whh + (size_t)j * kH + kk);            ST4(w[0], cc * 4, v);
        v = *reinterpret_cast<const float4*>(Whh + (size_t)(kH + j) * kH + kk);     ST4(w[1], cc * 4, v);
        v = *reinterpret_cast<const float4*>(Whh + (size_t)(2 * kH + j) * kH + kk); ST4(w[2], cc * 4, v);
    }
    const float bh0 = bhh[j];
    const float bh1 = bhh[kH + j];
    const float bh2 = bhh[2 * kH + j];

    const float* gbase = gi + (size_t)b * kT * kG;
    float gr[4], gz[4], gn[4];
#define LOADG(s, tt)                                              \
    do {                                                          \
        const int tc = ((tt) < len) ? (tt) : (len - 1);           \
        const float* gp = gbase + (size_t)tc * kG;                \
        gr[s] = gp[j]; gz[s] = gp[kH + j]; gn[s] = gp[2 * kH + j];\
    } while (0)
    LOADG(0, 0); LOADG(1, 1); LOADG(2, 2); LOADG(3, 3);

    if (tid < kH) hb[0][tid] = 0.0f;
    __syncthreads();

    int cur = 0;
    const int lenUp = (len + 3) & ~3;

#define ENC_STEP(s)                                                        \
    do {                                                                   \
        const int t = t0 + (s);                                            \
        float a0 = 0.f, a1 = 0.f, a2 = 0.f;                                \
        _Pragma("unroll")                                                  \
        for (int cc = 0; cc < 8; ++cc) {                                   \
            const float4 v = *reinterpret_cast<const float4*>(             \
                &hb[cur][kbase + (((cc + 2 * sub) & 7) << 2)]);            \
            FMA4(a0, w[0], cc * 4);                                        \
            FMA4(a1, w[1], cc * 4);                                        \
            FMA4(a2, w[2], cc * 4);                                        \
        }                                                                  \
        a0 += __shfl_xor(a0, 1); a0 += __shfl_xor(a0, 2);                  \
        a1 += __shfl_xor(a1, 1); a1 += __shfl_xor(a1, 2);                  \
        a2 += __shfl_xor(a2, 1); a2 += __shfl_xor(a2, 2);                  \
        const float hq = hb[cur][j];                                       \
        const float r = fsigmoid(gr[s] + a0 + bh0);                        \
        const float z = fsigmoid(gz[s] + a1 + bh1);                        \
        const float n = ftanh(gn[s] + r * (a2 + bh2));                     \
        const float hnew = (1.0f - z) * n + z * hq;                        \
        const float hc = (t < len) ? hnew : hq;                            \
        LOADG(s, t + 4);                                                   \
        const int nxt = cur ^ 1;                                           \
        if (sub == 0) hb[nxt][j] = hc;                                     \
        lds_barrier();                                                     \
        cur = nxt;                                                         \
    } while (0)

    for (int t0 = 0; t0 < lenUp; t0 += 4) {
        ENC_STEP(0); ENC_STEP(1); ENC_STEP(2); ENC_STEP(3);
    }
#undef ENC_STEP
#undef LOADG

    if (tid < kH) out[((size_t)b * kT + 1) * kH + tid] = hb[cur][tid];  // h_enc stash
}

// ================= encoder, fallback (x-path in loop) =================
__global__ __launch_bounds__(512, 2) void enc_fb_kernel(
    const float* __restrict__ to_x, const int* __restrict__ lengths,
    const float* __restrict__ Wih, const float* __restrict__ Whh,
    const float* __restrict__ bih, const float* __restrict__ bhh,
    float* __restrict__ out)
{
    __shared__ __align__(16) float hb2[2][132];
    __shared__ __align__(16) float xr[4][132];

    const int b = blockIdx.x;
    const int tid = threadIdx.x;
    const int j = tid >> 2;
    const int s4 = tid & 3;
    const int xh = s4 >> 1;
    const int sub = s4 & 1;
    const int len = lengths[b];
    const bool loader = (tid >= 480);
    const float* xrow = to_x + (size_t)b * kT * kH + (tid - 480) * 4;

    const float* W  = xh ? Whh : Wih;
    const float* bp = xh ? bhh : bih;

    float w[3][64];
#pragma unroll
    for (int r = 0; r < 3; ++r) {
        const float* rowp = W + (size_t)(r * kH + j) * kH + sub * 64;
#pragma unroll
        for (int k = 0; k < 64; k += 4) {
            const float4 v = *reinterpret_cast<const float4*>(rowp + k);
            ST4(w[r], k, v);
        }
    }
    const float bias0 = bp[j];
    const float bias1 = bp[kH + j];
    const float bias2 = bp[2 * kH + j];

    float4 xf0, xf1, xf2, xf3;
    if (tid < kH) hb2[0][tid] = 0.0f;
    if (loader) {
        xf0 = *reinterpret_cast<const float4*>(xrow + 0 * (size_t)kH);
        xf1 = *reinterpret_cast<const float4*>(xrow + 1 * (size_t)kH);
        xf2 = *reinterpret_cast<const float4*>(xrow + 2 * (size_t)kH);
        xf3 = *reinterpret_cast<const float4*>(xrow + 3 * (size_t)kH);
        *reinterpret_cast<float4*>(&xr[0][(tid - 480) * 4]) = xf0;
    }
    __syncthreads();

    int cur = 0;
    const int lenUp = (len + 3) & ~3;

#define FB_STEP(s, XFCUR, XFNEXT)                                          \
    do {                                                                   \
        const int t = t0 + (s);                                            \
        const float* src = (xh ? &hb2[cur][0] : &xr[s][0]) + sub * 64;     \
        float a0 = 0.f, a1 = 0.f, a2 = 0.f;                                \
        _Pragma("unroll")                                                  \
        for (int c = 0; c < 16; ++c) {                                     \
            const float4 v = *reinterpret_cast<const float4*>(src + c * 4);\
            FMA4(a0, w[0], c * 4);                                         \
            FMA4(a1, w[1], c * 4);                                         \
            FMA4(a2, w[2], c * 4);                                         \
        }                                                                  \
        a0 += __shfl_xor(a0, 1);                                           \
        a1 += __shfl_xor(a1, 1);                                           \
        a2 += __shfl_xor(a2, 1);                                           \
        a0 += bias0; a1 += bias1; a2 += bias2;                             \
        const float b0 = __shfl_xor(a0, 2);                                \
        const float b1 = __shfl_xor(a1, 2);                                \
        const float b2 = __shfl_xor(a2, 2);                                \
        const float hq  = hb2[cur][j];                                     \
        const float r   = fsigmoid(a0 + b0);                               \
        const float z   = fsigmoid(a1 + b1);                               \
        const float inn = xh ? b2 : a2;                                    \
        const float hn  = xh ? a2 : b2;                                    \
        const float n   = ftanh(inn + r * hn);                             \
        const float hnew = (1.0f - z) * n + z * hq;                        \
        const float hc = (t < len) ? hnew : hq;                            \
        if (loader) {                                                      \
            const int tc = ((t + 4) < len) ? (t + 4) : (len - 1);          \
            XFCUR = *reinterpret_cast<const float4*>(xrow + (size_t)tc * kH); \
        }                                                                  \
        const int nxt = cur ^ 1;                                           \
        if (s4 == 0) hb2[nxt][j] = hc;                                     \
        if (loader) *reinterpret_cast<float4*>(&xr[((s) + 1) & 3][(tid - 480) * 4]) = XFNEXT; \
        lds_barrier();                                                     \
        cur = nxt;                                                         \
    } while (0)

    for (int t0 = 0; t0 < lenUp; t0 += 4) {
        FB_STEP(0, xf0, xf1);
        FB_STEP(1, xf1, xf2);
        FB_STEP(2, xf2, xf3);
        FB_STEP(3, xf3, xf0);
    }
#undef FB_STEP

    if (tid < kH) out[((size_t)b * kT + 1) * kH + tid] = hb2[cur][tid];
}

// ================= fc + first decoder cell =================
__global__ void y0_kernel(
    const float* __restrict__ fcW, const float* __restrict__ fcb,
    const float* __restrict__ Wih, const float* __restrict__ Whh,
    const float* __restrict__ bih, const float* __restrict__ bhh,
    float* __restrict__ out)
{
    __shared__ float h[kH];
    __shared__ float enc[kH];
    __shared__ float gbuf[768];

    const int b = blockIdx.x;
    const int tid = threadIdx.x;

    if (tid < kH) h[tid] = out[((size_t)b * kT + 1) * kH + tid];
    __syncthreads();

    if (tid < kH) {
        float s = fcb[tid];
        const float* row = fcW + (size_t)tid * kH;
#pragma unroll 4
        for (int k = 0; k < kH; k += 4) {
            const float4 v = *reinterpret_cast<const float4*>(row + k);
            s = fmaf(v.x, h[k + 0], s);
            s = fmaf(v.y, h[k + 1], s);
            s = fmaf(v.z, h[k + 2], s);
            s = fmaf(v.w, h[k + 3], s);
        }
        enc[tid] = s;
    }
    __syncthreads();

    for (int rr = 0; rr < 3; ++rr) {
        const int row = tid + 256 * rr;          // 0..767
        const float* Wr;
        const float* src;
        float s;
        if (row < 384) { Wr = Wih + (size_t)row * kH;         src = enc; s = bih[row]; }
        else           { Wr = Whh + (size_t)(row - 384) * kH; src = h;   s = bhh[row - 384]; }
#pragma unroll 4
        for (int k = 0; k < kH; k += 4) {
            const float4 v = *reinterpret_cast<const float4*>(Wr + k);
            s = fmaf(v.x, src[k + 0], s);
            s = fmaf(v.y, src[k + 1], s);
            s = fmaf(v.z, src[k + 2], s);
            s = fmaf(v.w, src[k + 3], s);
        }
        gbuf[row] = s;
    }
    __syncthreads();

    if (tid < kH) {
        const float r = fsigmoid(gbuf[tid] + gbuf[384 + tid]);
        const float z = fsigmoid(gbuf[128 + tid] + gbuf[512 + tid]);
        const float n = ftanh(gbuf[256 + tid] + r * gbuf[640 + tid]);
        out[(size_t)b * kT * kH + tid] = (1.0f - z) * n + z * h[tid];
    }
}

// ================= decoder (stores h_t history; proj deferred) =================
__global__ __launch_bounds__(512, 2) void dec_kernel(
    const float* __restrict__ Wih, const float* __restrict__ Whh,
    const float* __restrict__ bih, const float* __restrict__ bhh,
    float* __restrict__ out)
{
    __shared__ __align__(16) float hb[2][128];

    const int b     = blockIdx.x;
    const int tid   = threadIdx.x;
    const int q     = tid >> 2;
    const int sub   = tid & 3;
    const int kbase = sub * 32;

    float w[4][32];
#pragma unroll
    for (int cc = 0; cc < 8; ++cc) {
        const int kk = kbase + (((cc + 2 * sub) & 7) << 2);
        float4 vi, vh;
        vi = *reinterpret_cast<const float4*>(Wih + (size_t)q * kH + kk);
        vh = *reinterpret_cast<const float4*>(Whh + (size_t)q * kH + kk);
        ST4ADD(w[0], cc * 4, vi, vh);
        vi = *reinterpret_cast<const float4*>(Wih + (size_t)(kH + q) * kH + kk);
        vh = *reinterpret_cast<const float4*>(Whh + (size_t)(kH + q) * kH + kk);
        ST4ADD(w[1], cc * 4, vi, vh);
        vi = *reinterpret_cast<const float4*>(Wih + (size_t)(2 * kH + q) * kH + kk);
        ST4(w[2], cc * 4, vi);
        vh = *reinterpret_cast<const float4*>(Whh + (size_t)(2 * kH + q) * kH + kk);
        ST4(w[3], cc * 4, vh);
    }
    const float brz0 = bih[q] + bhh[q];
    const float brz1 = bih[kH + q] + bhh[kH + q];
    const float bin  = bih[2 * kH + q];
    const float bhn  = bhh[2 * kH + q];

    if (tid < kH) hb[0][tid] = out[(size_t)b * kT * kH + tid];  // h_0 = y0
    __syncthreads();

    float* orow = out + (size_t)b * kT * kH + q;

    int cur = 0;
    for (int t = 1; t < kT; ++t) {
        float a0 = 0.f, a1 = 0.f, a2 = 0.f, a3 = 0.f;
#pragma unroll
        for (int cc = 0; cc < 8; ++cc) {
            const float4 v = *reinterpret_cast<const float4*>(
                &hb[cur][kbase + (((cc + 2 * sub) & 7) << 2)]);
            FMA4(a0, w[0], cc * 4);
            FMA4(a1, w[1], cc * 4);
            FMA4(a2, w[2], cc * 4);
            FMA4(a3, w[3], cc * 4);
        }
        a0 += __shfl_xor(a0, 1); a0 += __shfl_xor(a0, 2);
        a1 += __shfl_xor(a1, 1); a1 += __shfl_xor(a1, 2);
        a2 += __shfl_xor(a2, 1); a2 += __shfl_xor(a2, 2);
        a3 += __shfl_xor(a3, 1); a3 += __shfl_xor(a3, 2);

        const float hq = hb[cur][q];
        const float r = fsigmoid(a0 + brz0);
        const float z = fsigmoid(a1 + brz1);
        const float n = ftanh(a2 + bin + r * (a3 + bhn));
        const float hnew = (1.0f - z) * n + z * hq;

        const int nxt = cur ^ 1;
        if (sub == 0) {
            hb[nxt][q] = hnew;
            orow[(size_t)t * kH] = hnew;     // fire-and-forget h history
        }
        lds_barrier();
        cur = nxt;
    }
}

// ================= in-place output projection =================
__global__ __launch_bounds__(256, 1) void proj_kernel(
    const float* __restrict__ Wo, const float* __restrict__ ob,
    float* __restrict__ out)
{
    __shared__ float As[128][68];    // k-major h tile
    __shared__ float Ws[128][132];   // k-major Wo
    const int m0 = blockIdx.x * 64;
    const int tid = threadIdx.x;

#pragma unroll
    for (int jj = 0; jj < 8; ++jj) {
        const int i = tid + jj * 256;           // 0..2047
        const int r = i >> 5, cb = (i & 31) * 4;
        const float4 v = *reinterpret_cast<const float4*>(out + (size_t)(m0 + r) * kH + cb);
        As[cb + 0][r] = v.x; As[cb + 1][r] = v.y; As[cb + 2][r] = v.z; As[cb + 3][r] = v.w;
    }
#pragma unroll
    for (int jj = 0; jj < 16; ++jj) {
        const int i = tid + jj * 256;           // 0..4095
        const int o = i >> 5, cb = (i & 31) * 4;
        const float4 v = *reinterpret_cast<const float4*>(Wo + (size_t)o * kH + cb);
        Ws[cb + 0][o] = v.x; Ws[cb + 1][o] = v.y; Ws[cb + 2][o] = v.z; Ws[cb + 3][o] = v.w;
    }
    __syncthreads();

    const int tx = tid & 15, ty = tid >> 4;
    float acc[4][8] = {};
#pragma unroll 2
    for (int k = 0; k < 128; ++k) {
        const float4 a  = *reinterpret_cast<const float4*>(&As[k][ty * 4]);
        const float4 b0 = *reinterpret_cast<const float4*>(&Ws[k][tx * 4]);
        const float4 b1 = *reinterpret_cast<const float4*>(&Ws[k][64 + tx * 4]);
        const float av[4] = {a.x, a.y, a.z, a.w};
        const float bb[8] = {b0.x, b0.y, b0.z, b0.w, b1.x, b1.y, b1.z, b1.w};
#pragma unroll
        for (int r = 0; r < 4; ++r)
#pragma unroll
            for (int c = 0; c < 8; ++c) acc[r][c] = fmaf(av[r], bb[c], acc[r][c]);
    }
    const float4 o0 = *reinterpret_cast<const float4*>(ob + tx * 4);
    const float4 o1 = *reinterpret_cast<const float4*>(ob + 64 + tx * 4);
    const float ba[8] = {o0.x, o0.y, o0.z, o0.w, o1.x, o1.y, o1.z, o1.w};
#pragma unroll
    for (int r = 0; r < 4; ++r) {
        float4 s0, s1;
        s0.x = acc[r][0] + ba[0]; s0.y = acc[r][1] + ba[1];
        s0.z = acc[r][2] + ba[2]; s0.w = acc[r][3] + ba[3];
        s1.x = acc[r][4] + ba[4]; s1.y = acc[r][5] + ba[5];
        s1.z = acc[r][6] + ba[6]; s1.w = acc[r][7] + ba[7];
        float* rowp = out + (size_t)(m0 + ty * 4 + r) * kH;
        *reinterpret_cast<float4*>(rowp + tx * 4)      = s0;
        *reinterpret_cast<float4*>(rowp + 64 + tx * 4) = s1;
    }
}

}  // namespace

extern "C" void kernel_launch(void* const* d_in, const int* in_sizes, int n_in,
                              void* d_out, int out_size, void* d_ws, size_t ws_size,
                              hipStream_t stream) {
    (void)in_sizes; (void)n_in; (void)out_size;

    const float* to_x    = (const float*)d_in[0];
    const int*   lengths = (const int*)d_in[1];
    const float* eWih    = (const float*)d_in[2];
    const float* eWhh    = (const float*)d_in[3];
    const float* ebih    = (const float*)d_in[4];
    const float* ebhh    = (const float*)d_in[5];
    const float* fcW     = (const float*)d_in[6];
    const float* fcb     = (const float*)d_in[7];
    const float* dWih    = (const float*)d_in[8];
    const float* dWhh    = (const float*)d_in[9];
    const float* dbih    = (const float*)d_in[10];
    const float* dbhh    = (const float*)d_in[11];
    const float* oW      = (const float*)d_in[12];
    const float* obv     = (const float*)d_in[13];
    float* out = (float*)d_out;

    const size_t gi_bytes = kM * (size_t)kG * sizeof(float);   // ~201 MB
    if (ws_size >= gi_bytes) {
        float* gi = (float*)d_ws;
        gi_gemm<<<12288, 256, 0, stream>>>(to_x, eWih, ebih, gi);
        enc_gi_kernel<<<kB, 512, 0, stream>>>(gi, lengths, eWhh, ebhh, out);
    } else {
        enc_fb_kernel<<<kB, 512, 0, stream>>>(to_x, lengths, eWih, eWhh, ebih, ebhh, out);
    }
    y0_kernel<<<kB, 256, 0, stream>>>(fcW, fcb, dWih, dWhh, dbih, dbhh, out);
    dec_kernel<<<kB, 512, 0, stream>>>(dWih, dWhh, dbih, dbhh, out);
    proj_kernel<<<2048, 256, 0, stream>>>(oW, obv, out);
}